// Round 6
// baseline (243.977 us; speedup 1.0000x reference)
//
#include <hip/hip_runtime.h>
#include <math.h>

#define LOG2PI_F 1.8378770664093453f
#define LOG2E_F  1.4426950408889634f
#define LN2_F    0.6931471805599453f
#define EXP_NEG1 0.36787944117144233f

#define ROWF 52      // floats per AC row: a[16] mu[16] C[16] P pad[3]
#define JSP  64      // j slabs (k_pair grid.y)
#define JCH  32      // j rows per slab = B/JSP (B=2048)
#define ITI  256     // i per k_pair block (64 lanes x 4 MI)

__device__ __forceinline__ float exp2_(float x) { return __builtin_amdgcn_exp2f(x); }
__device__ __forceinline__ float log2_(float x) { return __builtin_amdgcn_logf(x); }

// ws layout (floats):
//   reconPart[512] @0   prepPart[256] @512   logsPart[64] @768   counter @832
//   AC[B*52] @1024      Racc[JSP*17*B] @1024+B*52
// Every read location is written first within the launch (counter zeroed in K1).

// ---------------- K1: prep (coeffs + lqzx/lprior partials) + recon fused ----
__global__ __launch_bounds__(256) void k_front(const float* __restrict__ mu,
                                               const float* __restrict__ lv,
                                               const float* __restrict__ z,
                                               const int* __restrict__ nds,
                                               const float4* __restrict__ x,
                                               const float4* __restrict__ r,
                                               float* __restrict__ ws,
                                               int B, int n4, int prepBlocks,
                                               int reconBlocks) {
    const int bx = blockIdx.x;
    if (bx == 0 && threadIdx.x == 0) *(int*)(ws + 832) = 0;   // K3 counter

    __shared__ float ra[4], rb[4];
    int lane = threadIdx.x & 63, wv = threadIdx.x >> 6;

    if (bx < prepBlocks) {
        float* AC = ws + 1024;
        float* prepPart = ws + 512;
        int idx = bx * 256 + threadIdx.x;
        int j = idx >> 4, d = idx & 15;
        float m = mu[idx], l = lv[idx], zz = z[idx];
        float is = __expf(-l);
        float a = -0.5f * LOG2E_F * is;                    // e = a*(v-m)^2 (log2)
        float ec = -0.5f * LOG2E_F * (l + LOG2PI_F);       // log2 of norm const

        float Nf = (float)(*nds);
        float Mf = (float)(B - 1);
        float strat = (Nf - Mf) / (Nf * Mf);
        float w = (j == 0) ? (1.0f / Nf) : ((j == 1) ? strat : (1.0f / Mf));

        float* row = AC + (size_t)j * ROWF;
        row[d] = a;
        row[16 + d] = m;
        row[32 + d] = w * exp2_(ec);
        float es = ec;
        es += __shfl_xor(es, 1); es += __shfl_xor(es, 2);
        es += __shfl_xor(es, 4); es += __shfl_xor(es, 8);
        if (d == 0) row[48] = w * exp2_(es);

        float t = zz - m;
        float ga = -0.5f * (fmaf(t * t, is, l) + LOG2PI_F);
        float gb = -0.5f * (fmaf(zz * zz, EXP_NEG1, 1.0f) + LOG2PI_F);
        #pragma unroll
        for (int off = 32; off > 0; off >>= 1) { ga += __shfl_down(ga, off); gb += __shfl_down(gb, off); }
        if (lane == 0) { ra[wv] = ga; rb[wv] = gb; }
        __syncthreads();
        if (threadIdx.x == 0) {
            prepPart[bx * 2 + 0] = ra[0] + ra[1] + ra[2] + ra[3];
            prepPart[bx * 2 + 1] = rb[0] + rb[1] + rb[2] + rb[3];
        }
    } else {
        float* reconPart = ws;
        int rbk = bx - prepBlocks;
        float s = 0.0f;
        for (int idx = rbk * 256 + threadIdx.x; idx < n4; idx += reconBlocks * 256) {
            float4 a = x[idx], b = r[idx];
            s += fabsf(a.x - b.x) + fabsf(a.y - b.y) + fabsf(a.z - b.z) + fabsf(a.w - b.w);
        }
        #pragma unroll
        for (int off = 32; off > 0; off >>= 1) s += __shfl_down(s, off);
        if (lane == 0) ra[wv] = s;
        __syncthreads();
        if (threadIdx.x == 0) reconPart[rbk] = ra[0] + ra[1] + ra[2] + ra[3];
    }
}

// ---------------- K2: pairwise accumulation, MI=4 register blocking ---------
// grid (B/256, JSP), block 256 = 4 waves. Lane owns 4 i's (q*64+lane within
// tile); waves split the 32-row slab 4x8. j-row coeffs broadcast from LDS:
// 13 ds_read_b128 serve 256 pairs (4x amortization vs rounds 4/5).
__global__ __launch_bounds__(256, 2) void k_pair(const float* __restrict__ AC,
                                                 const float* __restrict__ zg,
                                                 float* __restrict__ Racc, int B) {
    __shared__ float sAC[JCH * ROWF];                 // 6.5 KB
    __shared__ float red[4 * 2 * 64 * 21];            // 42 KB, stride 21 (2-way max)

    const int lane = threadIdx.x & 63;
    const int w    = threadIdx.x >> 6;
    const int ibase = blockIdx.x * ITI;

    // stage slab (contiguous, coalesced)
    {
        const float4* g = (const float4*)(AC + (size_t)blockIdx.y * JCH * ROWF);
        float4* s4 = (float4*)sAC;
        #pragma unroll
        for (int u = threadIdx.x; u < (JCH * ROWF) / 4; u += 256) s4[u] = g[u];
    }

    float v[4][16];
    #pragma unroll
    for (int q = 0; q < 4; ++q) {
        const float4* zp = (const float4*)(zg + (size_t)(ibase + q * 64 + lane) * 16);
        float4 a0 = zp[0], a1 = zp[1], a2 = zp[2], a3 = zp[3];
        v[q][0]=a0.x; v[q][1]=a0.y; v[q][2]=a0.z; v[q][3]=a0.w;
        v[q][4]=a1.x; v[q][5]=a1.y; v[q][6]=a1.z; v[q][7]=a1.w;
        v[q][8]=a2.x; v[q][9]=a2.y; v[q][10]=a2.z; v[q][11]=a2.w;
        v[q][12]=a3.x; v[q][13]=a3.y; v[q][14]=a3.z; v[q][15]=a3.w;
    }

    float sd[4][16], stot[4];
    #pragma unroll
    for (int q = 0; q < 4; ++q) {
        stot[q] = 0.0f;
        #pragma unroll
        for (int d = 0; d < 16; ++d) sd[q][d] = 0.0f;
    }

    __syncthreads();

    #pragma unroll 2
    for (int rr = 0; rr < JCH / 4; ++rr) {
        const float* rp = sAC + (w * (JCH / 4) + rr) * ROWF;   // wave-uniform
        float P = rp[48];
        float s2[4] = {0.0f, 0.0f, 0.0f, 0.0f};
        #pragma unroll
        for (int dq = 0; dq < 4; ++dq) {
            float4 aq = *(const float4*)(rp + dq * 4);
            float4 mq = *(const float4*)(rp + 16 + dq * 4);
            float4 cq = *(const float4*)(rp + 32 + dq * 4);
            #pragma unroll
            for (int q = 0; q < 4; ++q) {
                const int d0 = dq * 4;
                float t0 = v[q][d0+0] - mq.x; float e0 = (aq.x * t0) * t0;
                float t1 = v[q][d0+1] - mq.y; float e1 = (aq.y * t1) * t1;
                float t2 = v[q][d0+2] - mq.z; float e2 = (aq.z * t2) * t2;
                float t3 = v[q][d0+3] - mq.w; float e3 = (aq.w * t3) * t3;
                s2[q] += (e0 + e1) + (e2 + e3);
                sd[q][d0+0] = fmaf(cq.x, exp2_(e0), sd[q][d0+0]);
                sd[q][d0+1] = fmaf(cq.y, exp2_(e1), sd[q][d0+1]);
                sd[q][d0+2] = fmaf(cq.z, exp2_(e2), sd[q][d0+2]);
                sd[q][d0+3] = fmaf(cq.w, exp2_(e3), sd[q][d0+3]);
            }
        }
        #pragma unroll
        for (int q = 0; q < 4; ++q) stot[q] = fmaf(P, exp2_(s2[q]), stot[q]);
    }

    // 2-pass cross-wave reduction (q pairs), coalesced slab write
    #pragma unroll
    for (int p = 0; p < 2; ++p) {
        __syncthreads();
        #pragma unroll
        for (int qq = 0; qq < 2; ++qq) {
            int q = p * 2 + qq;
            float* wp = &red[(((w * 2 + qq) * 64) + lane) * 21];
            wp[0] = stot[q];
            #pragma unroll
            for (int d = 0; d < 16; ++d) wp[1 + d] = sd[q][d];
        }
        __syncthreads();
        for (int u = threadIdx.x; u < 2 * 64 * 17; u += 256) {
            int L = u & 63;
            int h = u >> 6;            // 0..33
            int c = h % 17, qq = h / 17;
            float ssum = red[(((0 * 2 + qq) * 64) + L) * 21 + c]
                       + red[(((1 * 2 + qq) * 64) + L) * 21 + c]
                       + red[(((2 * 2 + qq) * 64) + L) * 21 + c]
                       + red[(((3 * 2 + qq) * 64) + L) * 21 + c];
            int i2 = ibase + (p * 2 + qq) * 64 + L;
            Racc[((size_t)blockIdx.y * 17 + c) * B + i2] = ssum;
        }
    }
}

// ---------------- K3: slab-sum + logs + B-2 patch + last-block final --------
__global__ __launch_bounds__(256) void k_logs(float* __restrict__ ws,
                                              const float* __restrict__ zg,
                                              const int* __restrict__ nds,
                                              float* __restrict__ out,
                                              int B, float invBF, float invB) {
    float* reconPart = ws;
    float* prepPart  = ws + 512;
    float* logsPart  = ws + 768;
    int*   counter   = (int*)(ws + 832);
    const float* AC  = ws + 1024;
    const float* Racc = AC + (size_t)B * ROWF;

    const int lane = threadIdx.x & 63;
    const int g    = threadIdx.x >> 6;
    const int i    = blockIdx.x * 64 + lane;
    const int c0   = (g == 0) ? 0 : 1 + 4 * g;
    const int nc   = (g == 0) ? 5 : 4;

    float sums[5];
    #pragma unroll
    for (int k = 0; k < 5; ++k) sums[k] = 0.0f;
    #pragma unroll 4
    for (int s = 0; s < JSP; ++s) {
        for (int k = 0; k < nc; ++k)
            sums[k] += Racc[((size_t)s * 17 + c0 + k) * B + i];
    }

    if (i == B - 2) {
        const float* vv = zg + (size_t)(B - 2) * 16;
        float Nf = (float)(*nds);
        float Mf = (float)(B - 1);
        float dwN = (Nf - 2.0f * Mf) / Mf;            // (strat - 1/N) * N
        for (int k = 0; k < nc; ++k) {
            int c = c0 + k;
            if (c == 0) {
                float s2 = 0.0f;
                #pragma unroll
                for (int d = 0; d < 16; ++d) {
                    float t = vv[d] - AC[16 + d];
                    s2 += (AC[d] * t) * t;
                }
                sums[k] += dwN * AC[48] * exp2_(s2);
            } else {
                int d = c - 1;
                float t = vv[d] - AC[16 + d];
                sums[k] += dwN * AC[32 + d] * exp2_((AC[d] * t) * t);
            }
        }
    }

    float lqz = 0.0f, lqzp = 0.0f;
    for (int k = 0; k < nc; ++k) {
        float lg = log2_(sums[k]) * LN2_F;
        if (c0 + k == 0) lqz = lg; else lqzp += lg;
    }
    #pragma unroll
    for (int off = 32; off > 0; off >>= 1) {
        lqz  += __shfl_down(lqz, off);
        lqzp += __shfl_down(lqzp, off);
    }
    __shared__ float ra[4], rb[4];
    __shared__ int lastFlag;
    if (lane == 0) { ra[g] = lqz; rb[g] = lqzp; }
    __syncthreads();
    if (threadIdx.x == 0) {
        __hip_atomic_store(&logsPart[blockIdx.x * 2 + 0], ra[0] + ra[1] + ra[2] + ra[3],
                           __ATOMIC_RELEASE, __HIP_MEMORY_SCOPE_AGENT);
        __hip_atomic_store(&logsPart[blockIdx.x * 2 + 1], rb[0] + rb[1] + rb[2] + rb[3],
                           __ATOMIC_RELEASE, __HIP_MEMORY_SCOPE_AGENT);
        int old = __hip_atomic_fetch_add(counter, 1, __ATOMIC_ACQ_REL, __HIP_MEMORY_SCOPE_AGENT);
        lastFlag = (old == (int)gridDim.x - 1);
    }
    __syncthreads();

    if (lastFlag) {
        int t = threadIdx.x;
        float rec = 0.0f, lqzxS = 0.0f, lprS = 0.0f, lqzS = 0.0f, lqzpS = 0.0f;
        for (int k = t; k < 512; k += 256) rec += reconPart[k];
        if (t < 128) { lqzxS = prepPart[2 * t]; lprS = prepPart[2 * t + 1]; }
        if (t < 32) {
            lqzS  = __hip_atomic_load(&logsPart[2 * t + 0], __ATOMIC_ACQUIRE, __HIP_MEMORY_SCOPE_AGENT);
            lqzpS = __hip_atomic_load(&logsPart[2 * t + 1], __ATOMIC_ACQUIRE, __HIP_MEMORY_SCOPE_AGENT);
        }
        #pragma unroll
        for (int off = 32; off > 0; off >>= 1) {
            rec += __shfl_down(rec, off);     lqzxS += __shfl_down(lqzxS, off);
            lprS += __shfl_down(lprS, off);   lqzS  += __shfl_down(lqzS, off);
            lqzpS += __shfl_down(lqzpS, off);
        }
        __shared__ float fin[4][5];
        int ln = t & 63, wv = t >> 6;
        if (ln == 0) {
            fin[wv][0] = rec;  fin[wv][1] = lqzxS; fin[wv][2] = lprS;
            fin[wv][3] = lqzS; fin[wv][4] = lqzpS;
        }
        __syncthreads();
        if (t == 0) {
            float R = fin[0][0] + fin[1][0] + fin[2][0] + fin[3][0];
            float X = fin[0][1] + fin[1][1] + fin[2][1] + fin[3][1];
            float P = fin[0][2] + fin[1][2] + fin[2][2] + fin[3][2];
            float Q = fin[0][3] + fin[1][3] + fin[2][3] + fin[3][3];
            float D = fin[0][4] + fin[1][4] + fin[2][4] + fin[3][4];
            out[0] = R * invBF + (X + 3.0f * Q - 3.0f * D - P) * invB;
        }
    }
}

extern "C" void kernel_launch(void* const* d_in, const int* in_sizes, int n_in,
                              void* d_out, int out_size, void* d_ws, size_t ws_size,
                              hipStream_t stream) {
    const float* x   = (const float*)d_in[0];
    const float* rec = (const float*)d_in[1];
    const float* mu  = (const float*)d_in[2];
    const float* lv  = (const float*)d_in[3];
    const float* z   = (const float*)d_in[4];
    const int*   nds = (const int*)d_in[5];

    const int BD = in_sizes[2];        // B * 16
    const int B  = BD / 16;            // 2048
    const int BF = in_sizes[0];        // B * F
    const int n4 = BF / 4;

    float* ws  = (float*)d_ws;
    float* AC  = ws + 1024;
    float* Racc = AC + (size_t)B * ROWF;

    const int prepBlocks  = BD / 256;  // 128
    const int reconBlocks = 512;

    k_front<<<prepBlocks + reconBlocks, 256, 0, stream>>>(
        mu, lv, z, nds, (const float4*)x, (const float4*)rec, ws,
        B, n4, prepBlocks, reconBlocks);
    dim3 gp(B / ITI, JSP);
    k_pair<<<gp, 256, 0, stream>>>(AC, z, Racc, B);
    k_logs<<<B / 64, 256, 0, stream>>>(ws, z, nds, (float*)d_out,
                                       B, 1.0f / (float)BF, 1.0f / (float)B);
}

// Round 7
// 102.934 us; speedup vs baseline: 2.3702x; 2.3702x over previous
//
#include <hip/hip_runtime.h>
#include <math.h>

#define LOG2PI_F 1.8378770664093453f
#define LOG2E_F  1.4426950408889634f
#define LN2_F    0.6931471805599453f
#define EXP_NEG1 0.36787944117144233f

#define ROWF 52      // floats per AC row: a[16] mu[16] C[16] P pad[3]
#define JSP  32      // j slabs (k_pair grid.y)
#define JCH  64      // j rows per slab = B/JSP (B=2048), single LDS stage

__device__ __forceinline__ float exp2_(float x) { return __builtin_amdgcn_exp2f(x); }
__device__ __forceinline__ float log2_(float x) { return __builtin_amdgcn_logf(x); }

// ws layout (floats):
//   reconPart[512] @0   prepPart[256] @512   logsPart[136] @768   counter @960
//   AC[B*52] @1024      Racc[JSP*17*B] @1024+B*52  (4.5 MB)
// Every location read is written first within the launch (counter zeroed in k_front).

// ---------------- K1: prep (coeffs + lqzx/lprior partials) + recon fused ----
__global__ __launch_bounds__(256) void k_front(const float* __restrict__ mu,
                                               const float* __restrict__ lv,
                                               const float* __restrict__ z,
                                               const int* __restrict__ nds,
                                               const float4* __restrict__ x,
                                               const float4* __restrict__ r,
                                               float* __restrict__ ws,
                                               int B, int n4, int prepBlocks,
                                               int reconBlocks) {
    const int bx = blockIdx.x;
    if (bx == 0 && threadIdx.x == 0) *(int*)(ws + 960) = 0;   // k_logs counter

    __shared__ float ra[4], rb[4];
    int lane = threadIdx.x & 63, wv = threadIdx.x >> 6;

    if (bx < prepBlocks) {
        float* AC = ws + 1024;
        float* prepPart = ws + 512;
        int idx = bx * 256 + threadIdx.x;
        int j = idx >> 4, d = idx & 15;
        float m = mu[idx], l = lv[idx], zz = z[idx];
        float is = __expf(-l);
        float a = -0.5f * LOG2E_F * is;                    // e = a*(v-m)^2 (log2)
        float ec = -0.5f * LOG2E_F * (l + LOG2PI_F);       // log2 of norm const

        float Nf = (float)(*nds);
        float Mf = (float)(B - 1);
        float strat = (Nf - Mf) / (Nf * Mf);
        float w = (j == 0) ? (1.0f / Nf) : ((j == 1) ? strat : (1.0f / Mf));

        float* row = AC + (size_t)j * ROWF;
        row[d] = a;
        row[16 + d] = m;
        row[32 + d] = w * exp2_(ec);
        float es = ec;
        es += __shfl_xor(es, 1); es += __shfl_xor(es, 2);
        es += __shfl_xor(es, 4); es += __shfl_xor(es, 8);
        if (d == 0) row[48] = w * exp2_(es);

        float t = zz - m;
        float ga = -0.5f * (fmaf(t * t, is, l) + LOG2PI_F);
        float gb = -0.5f * (fmaf(zz * zz, EXP_NEG1, 1.0f) + LOG2PI_F);
        #pragma unroll
        for (int off = 32; off > 0; off >>= 1) { ga += __shfl_down(ga, off); gb += __shfl_down(gb, off); }
        if (lane == 0) { ra[wv] = ga; rb[wv] = gb; }
        __syncthreads();
        if (threadIdx.x == 0) {
            prepPart[bx * 2 + 0] = ra[0] + ra[1] + ra[2] + ra[3];
            prepPart[bx * 2 + 1] = rb[0] + rb[1] + rb[2] + rb[3];
        }
    } else {
        float* reconPart = ws;
        int rbk = bx - prepBlocks;
        float s = 0.0f;
        for (int idx = rbk * 256 + threadIdx.x; idx < n4; idx += reconBlocks * 256) {
            float4 a = x[idx], b = r[idx];
            s += fabsf(a.x - b.x) + fabsf(a.y - b.y) + fabsf(a.z - b.z) + fabsf(a.w - b.w);
        }
        #pragma unroll
        for (int off = 32; off > 0; off >>= 1) s += __shfl_down(s, off);
        if (lane == 0) ra[wv] = s;
        __syncthreads();
        if (threadIdx.x == 0) reconPart[rbk] = ra[0] + ra[1] + ra[2] + ra[3];
    }
}

// ---------------- K2: pairwise accumulation (round-4 structure, low VGPR) ---
// grid (B/16, JSP), block 256 = 16 il x 16 jg. One LDS stage of 64 rows.
// Each thread: 1 i, rows jg+16k (k<4). ~60 VGPRs -> no spill, high occupancy.
__global__ __launch_bounds__(256) void k_pair(const float* __restrict__ AC,
                                              const float* __restrict__ zg,
                                              float* __restrict__ Racc, int B) {
    __shared__ float sAC[JCH * ROWF];          // 13.3 KB
    __shared__ float red[4][16][17];           // 4.3 KB

    const int il = threadIdx.x & 15;
    const int jg = threadIdx.x >> 4;
    const int i  = blockIdx.x * 16 + il;

    // stage slab (contiguous, coalesced)
    {
        const float4* g = (const float4*)(AC + (size_t)blockIdx.y * JCH * ROWF);
        float4* s4 = (float4*)sAC;
        for (int u = threadIdx.x; u < (JCH * ROWF) / 4; u += 256) s4[u] = g[u];
    }

    float v[16];
    {
        const float4* zp = (const float4*)(zg + (size_t)i * 16);
        float4 a0 = zp[0], a1 = zp[1], a2 = zp[2], a3 = zp[3];
        v[0]=a0.x; v[1]=a0.y; v[2]=a0.z; v[3]=a0.w;
        v[4]=a1.x; v[5]=a1.y; v[6]=a1.z; v[7]=a1.w;
        v[8]=a2.x; v[9]=a2.y; v[10]=a2.z; v[11]=a2.w;
        v[12]=a3.x; v[13]=a3.y; v[14]=a3.z; v[15]=a3.w;
    }

    float sd[16];
    #pragma unroll
    for (int d = 0; d < 16; ++d) sd[d] = 0.0f;
    float stot = 0.0f;

    __syncthreads();

    #pragma unroll
    for (int k = 0; k < 4; ++k) {
        const float* rp = sAC + (jg + 16 * k) * ROWF;
        float P = rp[48];
        float s2 = 0.0f;
        #pragma unroll
        for (int dq = 0; dq < 4; ++dq) {
            float4 aq = *(const float4*)(rp + dq * 4);
            float4 mq = *(const float4*)(rp + 16 + dq * 4);
            float4 cq = *(const float4*)(rp + 32 + dq * 4);
            const int d0 = dq * 4;
            float t0 = v[d0+0] - mq.x; float e0 = (aq.x * t0) * t0;
            float t1 = v[d0+1] - mq.y; float e1 = (aq.y * t1) * t1;
            float t2 = v[d0+2] - mq.z; float e2 = (aq.z * t2) * t2;
            float t3 = v[d0+3] - mq.w; float e3 = (aq.w * t3) * t3;
            s2 += (e0 + e1) + (e2 + e3);
            sd[d0+0] = fmaf(cq.x, exp2_(e0), sd[d0+0]);
            sd[d0+1] = fmaf(cq.y, exp2_(e1), sd[d0+1]);
            sd[d0+2] = fmaf(cq.z, exp2_(e2), sd[d0+2]);
            sd[d0+3] = fmaf(cq.w, exp2_(e3), sd[d0+3]);
        }
        stot = fmaf(P, exp2_(s2), stot);
    }

    // reduce over jg-within-wave (lane bits 4-5), then cross-wave via LDS
    #pragma unroll
    for (int msk = 16; msk <= 32; msk <<= 1) {
        stot += __shfl_xor(stot, msk);
        #pragma unroll
        for (int d = 0; d < 16; ++d) sd[d] += __shfl_xor(sd[d], msk);
    }
    int lane = threadIdx.x & 63, wv = threadIdx.x >> 6;
    if (lane < 16) {
        red[wv][lane][0] = stot;
        #pragma unroll
        for (int d = 0; d < 16; ++d) red[wv][lane][1 + d] = sd[d];
    }
    __syncthreads();
    // 16*17 = 272 > 256: loop. il2 fastest -> 64B-coalesced slab stores.
    for (int t = threadIdx.x; t < 16 * 17; t += 256) {
        int il2 = t & 15, c = t >> 4;
        float s = red[0][il2][c] + red[1][il2][c] + red[2][il2][c] + red[3][il2][c];
        Racc[((size_t)blockIdx.y * 17 + c) * B + blockIdx.x * 16 + il2] = s;
    }
}

// ---------------- K3: one thread per (c,i): slab-sum + patch + log + final --
__global__ __launch_bounds__(256) void k_logs(float* __restrict__ ws,
                                              const float* __restrict__ zg,
                                              const int* __restrict__ nds,
                                              float* __restrict__ out,
                                              int B, float invBF, float invB) {
    float* reconPart = ws;
    float* prepPart  = ws + 512;
    float* logsPart  = ws + 768;
    int*   counter   = (int*)(ws + 960);
    const float* AC  = ws + 1024;
    const float* Racc = AC + (size_t)B * ROWF;

    int fl = blockIdx.x * 256 + threadIdx.x;     // < 17*B
    int c  = fl / B;
    int i  = fl - c * B;

    float s = 0.0f;
    #pragma unroll 8
    for (int sl = 0; sl < JSP; ++sl)
        s += Racc[((size_t)sl * 17 + c) * B + i];

    if (i == B - 2) {
        // prep folded w0 = 1/N into row 0, but W[B-2,0] = strat: add delta.
        const float* vv = zg + (size_t)(B - 2) * 16;
        float Nf = (float)(*nds);
        float Mf = (float)(B - 1);
        float dwN = (Nf - 2.0f * Mf) / Mf;        // (strat - 1/N) * N
        if (c == 0) {
            float s2 = 0.0f;
            #pragma unroll
            for (int d = 0; d < 16; ++d) {
                float t = vv[d] - AC[16 + d];
                s2 += (AC[d] * t) * t;
            }
            s += dwN * AC[48] * exp2_(s2);
        } else {
            int d = c - 1;
            float t = vv[d] - AC[16 + d];
            s += dwN * AC[32 + d] * exp2_((AC[d] * t) * t);
        }
    }

    // weighted log contribution: +3 for lqz (c==0), -3 for lqzp (c>=1)
    float contrib = ((c == 0) ? 3.0f : -3.0f) * log2_(s) * LN2_F;
    #pragma unroll
    for (int off = 32; off > 0; off >>= 1) contrib += __shfl_down(contrib, off);
    __shared__ float ra[4];
    __shared__ int lastFlag;
    int lane = threadIdx.x & 63, wv = threadIdx.x >> 6;
    if (lane == 0) ra[wv] = contrib;
    __syncthreads();
    if (threadIdx.x == 0) {
        __hip_atomic_store(&logsPart[blockIdx.x], ra[0] + ra[1] + ra[2] + ra[3],
                           __ATOMIC_RELEASE, __HIP_MEMORY_SCOPE_AGENT);
        int old = __hip_atomic_fetch_add(counter, 1, __ATOMIC_ACQ_REL, __HIP_MEMORY_SCOPE_AGENT);
        lastFlag = (old == (int)gridDim.x - 1);
    }
    __syncthreads();

    if (lastFlag) {
        int t = threadIdx.x;
        float rec = 0.0f, X = 0.0f, P = 0.0f, QD = 0.0f;
        for (int k = t; k < 512; k += 256) rec += reconPart[k];
        if (t < 128) { X = prepPart[2 * t]; P = prepPart[2 * t + 1]; }
        if (t < (int)gridDim.x)
            QD = __hip_atomic_load(&logsPart[t], __ATOMIC_ACQUIRE, __HIP_MEMORY_SCOPE_AGENT);
        #pragma unroll
        for (int off = 32; off > 0; off >>= 1) {
            rec += __shfl_down(rec, off);
            X   += __shfl_down(X, off);
            P   += __shfl_down(P, off);
            QD  += __shfl_down(QD, off);
        }
        __shared__ float fin[4][4];
        int ln = t & 63, w2 = t >> 6;
        if (ln == 0) { fin[w2][0] = rec; fin[w2][1] = X; fin[w2][2] = P; fin[w2][3] = QD; }
        __syncthreads();
        if (t == 0) {
            float R  = fin[0][0] + fin[1][0] + fin[2][0] + fin[3][0];
            float Xs = fin[0][1] + fin[1][1] + fin[2][1] + fin[3][1];
            float Ps = fin[0][2] + fin[1][2] + fin[2][2] + fin[3][2];
            float Qs = fin[0][3] + fin[1][3] + fin[2][3] + fin[3][3];
            out[0] = R * invBF + (Xs - Ps + Qs) * invB;
        }
    }
}

extern "C" void kernel_launch(void* const* d_in, const int* in_sizes, int n_in,
                              void* d_out, int out_size, void* d_ws, size_t ws_size,
                              hipStream_t stream) {
    const float* x   = (const float*)d_in[0];
    const float* rec = (const float*)d_in[1];
    const float* mu  = (const float*)d_in[2];
    const float* lv  = (const float*)d_in[3];
    const float* z   = (const float*)d_in[4];
    const int*   nds = (const int*)d_in[5];

    const int BD = in_sizes[2];        // B * 16
    const int B  = BD / 16;            // 2048
    const int BF = in_sizes[0];        // B * F
    const int n4 = BF / 4;

    float* ws   = (float*)d_ws;
    float* AC   = ws + 1024;
    float* Racc = AC + (size_t)B * ROWF;

    const int prepBlocks  = BD / 256;  // 128
    const int reconBlocks = 512;

    k_front<<<prepBlocks + reconBlocks, 256, 0, stream>>>(
        mu, lv, z, nds, (const float4*)x, (const float4*)rec, ws,
        B, n4, prepBlocks, reconBlocks);
    dim3 gp(B / 16, JSP);
    k_pair<<<gp, 256, 0, stream>>>(AC, z, Racc, B);
    k_logs<<<(17 * B) / 256, 256, 0, stream>>>(ws, z, nds, (float*)d_out,
                                               B, 1.0f / (float)BF, 1.0f / (float)B);
}